// Round 9
// baseline (710.979 us; speedup 1.0000x reference)
//
#include <hip/hip_runtime.h>

typedef __attribute__((ext_vector_type(8))) __bf16 bf16x8;
typedef __attribute__((ext_vector_type(4))) float f32x4;
typedef __attribute__((ext_vector_type(4))) unsigned int u32x4;

#define NV 100000
#define NE 400000
#define NT16 (NE / 16)   // 25000 16-edge tiles per batch

// d_ws layout: [0, VTAB_BYTES) bf16 vdata table; [VTAB_BYTES, +2048) hc table
#define VTAB_ELEMS ((size_t)4 * NV * 64)
#define VTAB_BYTES (VTAB_ELEMS * 2)
#define WS_NEED (VTAB_BYTES + 2048)

// LDS (main kernel): exactly 64 KiB -> 2 blocks/CU at 512 threads
#define W1T_OFF 0        // 128 rows (hid) x 384B (192 din bf16, swizzled)
#define W2T_OFF 49152    // 64 rows (dout) x 256B (128 hid bf16, k-permuted + swizzled)
#define LDS_SIZE 65536

__device__ inline unsigned short f2b_rne(float f) {
    unsigned u = __builtin_bit_cast(unsigned, f);
    return (unsigned short)((u + 0x7fffu + ((u >> 16) & 1u)) >> 16);
}

__device__ inline unsigned pk2(float lo, float hi) {
    unsigned r;
    asm("v_cvt_pk_bf16_f32 %0, %1, %2" : "=v"(r) : "v"(lo), "v"(hi));
    return r;
}

__device__ inline bf16x8 pack8(f32x4 a, f32x4 b) {
    u32x4 u = {pk2(a[0], a[1]), pk2(a[2], a[3]), pk2(b[0], b[1]), pk2(b[2], b[3])};
    return __builtin_bit_cast(bf16x8, u);
}

__device__ inline f32x4 ldv(const float* p) { return *(const f32x4*)p; }
__device__ inline f32x4 ntl(const float* p) { return __builtin_nontemporal_load((const f32x4*)p); }

__device__ inline bf16x8 load8(const float* p) {
    f32x4 x = *(const f32x4*)p;
    f32x4 y = *(const f32x4*)(p + 4);
    return pack8(x, y);
}

// ---- pre-pass 1: vdata f32 -> bf16 table ----
__global__ __launch_bounds__(256) void vconv_kernel(const float* __restrict__ vdata,
                                                    unsigned short* __restrict__ vt)
{
    const size_t G = VTAB_ELEMS / 8;
    for (size_t g = (size_t)blockIdx.x * blockDim.x + threadIdx.x; g < G;
         g += (size_t)gridDim.x * blockDim.x) {
        const float* p = vdata + g * 8;
        *(bf16x8*)(vt + g * 8) = pack8(ldv(p), ldv(p + 4));
    }
}

// ---- pre-pass 2: hc[b][hid] = b1[hid] + sum_j cdata[b][j] * W1[192+j][hid] ----
__global__ __launch_bounds__(512) void hc_kernel(const float* __restrict__ W1,
                                                 const float* __restrict__ b1,
                                                 const float* __restrict__ cdata,
                                                 float* __restrict__ hc)
{
    const int tid = threadIdx.x;
    const int b = tid >> 7, hid = tid & 127;
    float s = b1[hid];
#pragma unroll 8
    for (int j = 0; j < 64; ++j)
        s += cdata[b * 64 + j] * W1[(192 + j) * 128 + hid];
    hc[b * 128 + hid] = s;
}

// ===================== main kernel: 16-edge tiles + spill-free vt prefetch =====================
// Swapped formulation: h^T = mfma(A=W1^T frag, B=etin^T gather); edge index
// lane-local (col=l15). Layer-2 B-frag slot (lg,j) of chunk kc2 holds
// hid = kc2*32 + (j>>2)*16 + lg*4 + (j&3); absorbed into W2T init layout.
// Context+b1 folded into hc => kc runs 0..5 only.
// 16-edge tiles (et dim removed) so the full vt prefetch fits the 128-VGPR
// budget: acc1 32 + vt-cur 16 + vt-next 16 + edata 16 + q/acc2 32 ~= 110.
// Layer-1 consumes prefetched vt chunks FIRST (kc 2..5), fresh edata LAST
// (kc 0..1) - accumulation order is free - so edata latency is covered.

#define VT_GATHER(S0, R0, d2, d3, d4, d5) { \
    const unsigned short* s0_ = vt_b + (size_t)(S0) * 64 + lg * 8; \
    const unsigned short* r0_ = vt_b + (size_t)(R0) * 64 + lg * 8; \
    d2 = *(const bf16x8*)(s0_);      d3 = *(const bf16x8*)(s0_ + 32); \
    d4 = *(const bf16x8*)(r0_);      d5 = *(const bf16x8*)(r0_ + 32); }

#define L1STEP(KC, BC) { \
    _Pragma("unroll") \
    for (int ht = 0; ht < 8; ++ht) { \
        const int row = ht * 16 + l15; \
        const bf16x8 wf = *(const bf16x8*)(lds + W1T_OFF + row * 384 + \
            (((KC) * 64 + lg * 16) ^ ((row & 7) << 4))); \
        acc1[ht] = __builtin_amdgcn_mfma_f32_16x16x32_bf16(wf, BC, acc1[ht], 0, 0, 0); \
    } }

__global__ __launch_bounds__(512, 4) void edgeblock_kernel(
    const unsigned short* __restrict__ vt, const float* __restrict__ hc,
    const float* __restrict__ edata, const float* __restrict__ W1,
    const float* __restrict__ W2, const float* __restrict__ b2,
    const int* __restrict__ snd, const int* __restrict__ rcv,
    float* __restrict__ out)
{
    __shared__ __align__(16) unsigned char lds[LDS_SIZE];
    const int tid = threadIdx.x;
    const int lane = tid & 63;
    const int w = tid >> 6;
    const int l15 = lane & 15;
    const int lg = lane >> 4;

    // XCD-aware batch pinning: batch b -> XCD pair {2b, 2b+1}
    const int bid = blockIdx.x;
    const int xcd = bid & 7;
    const int b   = xcd >> 1;
    const int blk = ((bid >> 3) << 1) | (xcd & 1);

    // ---- one-time init: W1^T rows k<192 (384B stride), W2^T k-permuted ----
    for (int i = tid; i < 192 * 128; i += 512) {
        int k = i >> 7, n = i & 127;
        *(unsigned short*)(lds + W1T_OFF + n * 384 + ((k * 2) ^ ((n & 7) << 4))) = f2b_rne(W1[i]);
    }
    for (int i = tid; i < 128 * 64; i += 512) {
        int k = i >> 6, n = i & 63;
        int kc2 = k >> 5, c = k & 31;
        int j   = ((c >> 4) << 2) | (c & 3);
        int lgs = (c >> 2) & 3;
        int off = kc2 * 64 + lgs * 16 + j * 2;
        *(unsigned short*)(lds + W2T_OFF + n * 256 + (off ^ ((n & 7) << 4))) = f2b_rne(W2[i]);
    }
    __syncthreads();

    const size_t bE = (size_t)b * NE;
    const float* ed_b = edata + bE * 64;
    const unsigned short* vt_b = vt + (size_t)b * NV * 64;
    const float* hc_b = hc + b * 128;
    const int* snd_b = snd + bE;
    const int* rcv_b = rcv + bE;
    float* out_b = out + bE * 64;

    int t = blk * 8 + w;                 // start tile, stride 1024, < NT16

    // ---- prologue: gather tile t (cold) + prefetch tile t+1024's indices ----
    bf16x8 a2, a3, a4, a5;
    {
        const int e0 = t * 16;
        const int s0 = snd_b[e0 + l15];
        const int r0 = rcv_b[e0 + l15];
        VT_GATHER(s0, r0, a2, a3, a4, a5);
    }
    int tn = t + 1024;
    bool more = tn < NT16;
    int nS0 = 0, nR0 = 0;
    if (more) {
        const int en = tn * 16;
        nS0 = snd_b[en + l15];
        nR0 = rcv_b[en + l15];
    }

    for (;;) {
        // ---- issue next tile's vt gather FIRST (max latency cover) ----
        bf16x8 nb2, nb3, nb4, nb5;
        if (more) {
            VT_GATHER(nS0, nR0, nb2, nb3, nb4, nb5);
            const int tq = tn + 1024;
            if (tq < NT16) {
                const int eq = tq * 16;
                nS0 = snd_b[eq + l15];
                nR0 = rcv_b[eq + l15];
            }
        }

        // ---- current tile's edata (consumed LAST in layer 1) ----
        const int e0 = t * 16;
        const float* er0 = ed_b + (size_t)(e0 + l15) * 64 + lg * 8;
        f32x4 g0 = ntl(er0),      g1 = ntl(er0 + 4);
        f32x4 g2 = ntl(er0 + 32), g3 = ntl(er0 + 36);

        // acc init = hc (context + b1 folded), L1-hot
        f32x4 acc1[8];
#pragma unroll
        for (int ht = 0; ht < 8; ++ht)
            acc1[ht] = ldv(hc_b + ht * 16 + lg * 4);

        // ---- layer 1: prefetched vt chunks first, edata last ----
        L1STEP(2, a2)
        L1STEP(3, a3)
        L1STEP(4, a4)
        L1STEP(5, a5)
        {
            bf16x8 e00 = pack8(g0, g1);
            L1STEP(0, e00)
        }
        {
            bf16x8 e10 = pack8(g2, g3);
            L1STEP(1, e10)
        }

        // ---- relu + pack h^T into layer-2 B fragments ----
        bf16x8 q[4];
#pragma unroll
        for (int kc2 = 0; kc2 < 4; ++kc2) {
            f32x4 u = acc1[2 * kc2], v = acc1[2 * kc2 + 1];
            u32x4 pq;
            pq[0] = pk2(fmaxf(u[0], 0.f), fmaxf(u[1], 0.f));
            pq[1] = pk2(fmaxf(u[2], 0.f), fmaxf(u[3], 0.f));
            pq[2] = pk2(fmaxf(v[0], 0.f), fmaxf(v[1], 0.f));
            pq[3] = pk2(fmaxf(v[2], 0.f), fmaxf(v[3], 0.f));
            q[kc2] = __builtin_bit_cast(bf16x8, pq);
        }

        // ---- layer 2: out^T = W2^T @ h^T ----
        f32x4 acc2[4];
#pragma unroll
        for (int dt = 0; dt < 4; ++dt)
            acc2[dt] = ldv(b2 + dt * 16 + lg * 4);
#pragma unroll
        for (int kc2 = 0; kc2 < 4; ++kc2)
#pragma unroll
            for (int dt = 0; dt < 4; ++dt) {
                const int row = dt * 16 + l15;
                const bf16x8 wf = *(const bf16x8*)(lds + W2T_OFF + row * 256 +
                                                   ((kc2 * 64 + lg * 16) ^ ((row & 7) << 4)));
                acc2[dt] = __builtin_amdgcn_mfma_f32_16x16x32_bf16(wf, q[kc2], acc2[dt], 0, 0, 0);
            }

        // ---- store tile t ----
        {
            float* ob0 = out_b + (size_t)(e0 + l15) * 64 + lg * 4;
#pragma unroll
            for (int dt = 0; dt < 4; ++dt)
                *(f32x4*)(ob0 + dt * 16) = acc2[dt];
        }

        if (!more) break;
        a2 = nb2; a3 = nb3; a4 = nb4; a5 = nb5;
        t = tn; tn += 1024; more = tn < NT16;
    }
}

// ===================== legacy fallback (round-4 kernel, proven 336 us) =====================
__global__ __launch_bounds__(512, 4) void edgeblock_legacy(
    const float* __restrict__ vdata, const float* __restrict__ edata,
    const float* __restrict__ cdata, const float* __restrict__ W1,
    const float* __restrict__ b1, const float* __restrict__ W2,
    const float* __restrict__ b2, const int* __restrict__ snd,
    const int* __restrict__ rcv, float* __restrict__ out)
{
    __shared__ __align__(16) unsigned char lds[81920];
    const int tid = threadIdx.x;
    const int lane = tid & 63;
    const int w = tid >> 6;
    const int l15 = lane & 15;
    const int lg = lane >> 4;
    const int bid = blockIdx.x;
    const int xcd = bid & 7;
    const int b   = xcd >> 1;
    const int blk = ((bid >> 3) << 1) | (xcd & 1);

    for (int i = tid; i < 256 * 128; i += 512) {
        int k = i >> 7, n = i & 127;
        *(unsigned short*)(lds + n * 512 + ((k * 2) ^ ((n & 7) << 4))) = f2b_rne(W1[i]);
    }
    for (int i = tid; i < 128 * 64; i += 512) {
        int k = i >> 6, n = i & 63;
        int kc2 = k >> 5, c = k & 31;
        int j   = ((c >> 4) << 2) | (c & 3);
        int lgs = (c >> 2) & 3;
        int off = kc2 * 64 + lgs * 16 + j * 2;
        *(unsigned short*)(lds + 65536 + n * 256 + (off ^ ((n & 7) << 4))) = f2b_rne(W2[i]);
    }
    __syncthreads();

    const float* cd = cdata + b * 64;
    const bf16x8 cfr0 = load8(cd + lg * 8);
    const bf16x8 cfr1 = load8(cd + 32 + lg * 8);

    const size_t bE = (size_t)b * NE;
    const float* ed_b = edata + bE * 64;
    const float* vd_b = vdata + (size_t)b * NV * 64;
    const int* snd_b = snd + bE;
    const int* rcv_b = rcv + bE;
    float* out_b = out + bE * 64;

    for (int t = blk * 8 + w; t < NE / 32; t += 1024) {
        const int e0 = t * 32;
        const int sid0 = snd_b[e0 + l15], sid1 = snd_b[e0 + 16 + l15];
        const int rid0 = rcv_b[e0 + l15], rid1 = rcv_b[e0 + 16 + l15];
        const float* er0 = ed_b + (size_t)(e0 + l15) * 64 + lg * 8;
        const float* er1 = er0 + 16 * 64;
        const float* sr0 = vd_b + (size_t)sid0 * 64 + lg * 8;
        const float* sr1 = vd_b + (size_t)sid1 * 64 + lg * 8;
        const float* rr0 = vd_b + (size_t)rid0 * 64 + lg * 8;
        const float* rr1 = vd_b + (size_t)rid1 * 64 + lg * 8;

        bf16x8 af[6][2];
        af[0][0] = load8(er0);      af[0][1] = load8(er1);
        af[1][0] = load8(er0 + 32); af[1][1] = load8(er1 + 32);
        af[2][0] = load8(sr0);      af[2][1] = load8(sr1);
        af[3][0] = load8(sr0 + 32); af[3][1] = load8(sr1 + 32);
        af[4][0] = load8(rr0);      af[4][1] = load8(rr1);
        af[5][0] = load8(rr0 + 32); af[5][1] = load8(rr1 + 32);

        f32x4 acc1[8][2];
#pragma unroll
        for (int ht = 0; ht < 8; ++ht) {
            f32x4 bv = ldv(b1 + ht * 16 + lg * 4);
            acc1[ht][0] = bv; acc1[ht][1] = bv;
        }
#pragma unroll
        for (int kc = 0; kc < 8; ++kc) {
            bf16x8 bc0, bc1;
            if (kc < 6)      { bc0 = af[kc][0]; bc1 = af[kc][1]; }
            else if (kc == 6){ bc0 = cfr0;      bc1 = cfr0; }
            else             { bc0 = cfr1;      bc1 = cfr1; }
#pragma unroll
            for (int ht = 0; ht < 8; ++ht) {
                const int row = ht * 16 + l15;
                const bf16x8 wf = *(const bf16x8*)(lds + row * 512 +
                                                   ((kc * 64 + lg * 16) ^ ((row & 7) << 4)));
                acc1[ht][0] = __builtin_amdgcn_mfma_f32_16x16x32_bf16(wf, bc0, acc1[ht][0], 0, 0, 0);
                acc1[ht][1] = __builtin_amdgcn_mfma_f32_16x16x32_bf16(wf, bc1, acc1[ht][1], 0, 0, 0);
            }
        }

        bf16x8 q[2][4];
#pragma unroll
        for (int kc2 = 0; kc2 < 4; ++kc2)
#pragma unroll
            for (int et = 0; et < 2; ++et) {
                f32x4 u = acc1[2 * kc2][et], v = acc1[2 * kc2 + 1][et];
                u32x4 pq;
                pq[0] = pk2(fmaxf(u[0], 0.f), fmaxf(u[1], 0.f));
                pq[1] = pk2(fmaxf(u[2], 0.f), fmaxf(u[3], 0.f));
                pq[2] = pk2(fmaxf(v[0], 0.f), fmaxf(v[1], 0.f));
                pq[3] = pk2(fmaxf(v[2], 0.f), fmaxf(v[3], 0.f));
                q[et][kc2] = __builtin_bit_cast(bf16x8, pq);
            }

        f32x4 acc2[4][2];
#pragma unroll
        for (int dt = 0; dt < 4; ++dt) {
            f32x4 bv = ldv(b2 + dt * 16 + lg * 4);
            acc2[dt][0] = bv; acc2[dt][1] = bv;
        }
#pragma unroll
        for (int kc2 = 0; kc2 < 4; ++kc2)
#pragma unroll
            for (int dt = 0; dt < 4; ++dt) {
                const int row = dt * 16 + l15;
                const bf16x8 wf = *(const bf16x8*)(lds + 65536 + row * 256 +
                                                   ((kc2 * 64 + lg * 16) ^ ((row & 7) << 4)));
                acc2[dt][0] = __builtin_amdgcn_mfma_f32_16x16x32_bf16(wf, q[0][kc2], acc2[dt][0], 0, 0, 0);
                acc2[dt][1] = __builtin_amdgcn_mfma_f32_16x16x32_bf16(wf, q[1][kc2], acc2[dt][1], 0, 0, 0);
            }

        float* ob0 = out_b + (size_t)(e0 + l15) * 64 + lg * 4;
        float* ob1 = ob0 + 16 * 64;
#pragma unroll
        for (int dt = 0; dt < 4; ++dt) {
            *(f32x4*)(ob0 + dt * 16) = acc2[dt][0];
            *(f32x4*)(ob1 + dt * 16) = acc2[dt][1];
        }
    }
}

extern "C" void kernel_launch(void* const* d_in, const int* in_sizes, int n_in,
                              void* d_out, int out_size, void* d_ws, size_t ws_size,
                              hipStream_t stream) {
    const float* vdata = (const float*)d_in[0];
    const float* edata = (const float*)d_in[1];
    const float* cdata = (const float*)d_in[2];
    const float* W1    = (const float*)d_in[3];
    const float* b1    = (const float*)d_in[4];
    const float* W2    = (const float*)d_in[5];
    const float* b2    = (const float*)d_in[6];
    const int*   snd   = (const int*)d_in[7];
    const int*   rcv   = (const int*)d_in[8];
    float* out = (float*)d_out;

    if (ws_size >= WS_NEED) {
        unsigned short* vt = (unsigned short*)d_ws;
        float* hc = (float*)((char*)d_ws + VTAB_BYTES);
        vconv_kernel<<<dim3(2048), dim3(256), 0, stream>>>(vdata, vt);
        hc_kernel<<<dim3(1), dim3(512), 0, stream>>>(W1, b1, cdata, hc);
        edgeblock_kernel<<<dim3(512), dim3(512), 0, stream>>>(
            vt, hc, edata, W1, W2, b2, snd, rcv, out);
    } else {
        edgeblock_legacy<<<dim3(512), dim3(512), 0, stream>>>(
            vdata, edata, cdata, W1, b1, W2, b2, snd, rcv, out);
    }
}

// Round 10
// 309.177 us; speedup vs baseline: 2.2996x; 2.2996x over previous
//
#include <hip/hip_runtime.h>

typedef __attribute__((ext_vector_type(8))) __bf16 bf16x8;
typedef __attribute__((ext_vector_type(4))) float f32x4;
typedef __attribute__((ext_vector_type(4))) unsigned int u32x4;

#define NV 100000
#define NE 400000
#define NT (NE / 32)

// bf16 vdata table in d_ws
#define VTAB_ELEMS ((size_t)4 * NV * 64)
#define VTAB_BYTES (VTAB_ELEMS * 2)

// LDS layout (bytes): exactly 80 KiB -> 2 blocks/CU at 512 threads
#define W1T_OFF 0        // 128 rows (hid) x 512B (256 din bf16, swizzled)
#define W2T_OFF 65536    // 64 rows (dout) x 256B (128 hid bf16, k-permuted + swizzled)
#define LDS_SIZE 81920

__device__ inline unsigned short f2b_rne(float f) {
    unsigned u = __builtin_bit_cast(unsigned, f);
    return (unsigned short)((u + 0x7fffu + ((u >> 16) & 1u)) >> 16);
}

__device__ inline unsigned pk2(float lo, float hi) {
    unsigned r;
    asm("v_cvt_pk_bf16_f32 %0, %1, %2" : "=v"(r) : "v"(lo), "v"(hi));
    return r;
}

__device__ inline bf16x8 pack8(f32x4 a, f32x4 b) {
    u32x4 u = {pk2(a[0], a[1]), pk2(a[2], a[3]), pk2(b[0], b[1]), pk2(b[2], b[3])};
    return __builtin_bit_cast(bf16x8, u);
}

__device__ inline f32x4 ldv(const float* p) { return *(const f32x4*)p; }
__device__ inline f32x4 ntl(const float* p) { return __builtin_nontemporal_load((const f32x4*)p); }
__device__ inline void nts(float* p, f32x4 v) { __builtin_nontemporal_store(v, (f32x4*)p); }

__device__ inline bf16x8 load8(const float* p) {
    f32x4 x = *(const f32x4*)p;
    f32x4 y = *(const f32x4*)(p + 4);
    return pack8(x, y);
}

// ---- pre-pass: vdata f32 -> bf16 table (RNE, identical to main-path pk2) ----
__global__ __launch_bounds__(256) void vconv_kernel(const float* __restrict__ vdata,
                                                    unsigned short* __restrict__ vt)
{
    const size_t G = VTAB_ELEMS / 8;
    for (size_t g = (size_t)blockIdx.x * blockDim.x + threadIdx.x; g < G;
         g += (size_t)gridDim.x * blockDim.x) {
        const float* p = vdata + g * 8;
        *(bf16x8*)(vt + g * 8) = pack8(ldv(p), ldv(p + 4));
    }
}

// ===================== main kernel: R5 structure (proven best, 280 us main)
//                       + nontemporal out stores =====================
// Swapped formulation: h^T = mfma(A=W1^T frag, B=etin^T gather); edge index is
// lane-local (col=l15). Layer-2 B-frag slot (lg,j) of chunk kc2 holds
// hid = kc2*32 + (j>>2)*16 + lg*4 + (j&3) with zero cross-lane ops; that
// permutation is absorbed into W2T's init-time layout.
// NO prefetch/pipelining: R8 proved it spills at the 128-VGPR budget; R9
// proved L2-thrash when it fits. Upfront same-tile gather is the optimum.
template <int BF16V>
__global__ __launch_bounds__(512, 4) void edgeblock_kernel(
    const float* __restrict__ vdata, const unsigned short* __restrict__ vt,
    const float* __restrict__ edata,
    const float* __restrict__ cdata, const float* __restrict__ W1,
    const float* __restrict__ b1, const float* __restrict__ W2,
    const float* __restrict__ b2, const int* __restrict__ snd,
    const int* __restrict__ rcv, float* __restrict__ out)
{
    __shared__ __align__(16) unsigned char lds[LDS_SIZE];
    const int tid = threadIdx.x;
    const int lane = tid & 63;
    const int w = tid >> 6;
    const int l15 = lane & 15;
    const int lg = lane >> 4;

    // XCD-aware batch pinning: batch b -> XCD pair {2b, 2b+1}; each batch's
    // 12.8 MB bf16 vdata table gets 8 MB of private L2.
    const int bid = blockIdx.x;
    const int xcd = bid & 7;
    const int b   = xcd >> 1;
    const int blk = ((bid >> 3) << 1) | (xcd & 1);

    // ---- one-time init: W1^T (swizzled), W2^T (k-permuted + swizzled) ----
    for (int i = tid; i < 256 * 128; i += 512) {
        int k = i >> 7, n = i & 127;
        *(unsigned short*)(lds + W1T_OFF + n * 512 + ((k * 2) ^ ((n & 7) << 4))) = f2b_rne(W1[i]);
    }
    for (int i = tid; i < 128 * 64; i += 512) {
        int k = i >> 6, n = i & 63;
        int kc2 = k >> 5, c = k & 31;
        int j   = ((c >> 4) << 2) | (c & 3);
        int lgs = (c >> 2) & 3;
        int off = kc2 * 64 + lgs * 16 + j * 2;
        *(unsigned short*)(lds + W2T_OFF + n * 256 + (off ^ ((n & 7) << 4))) = f2b_rne(W2[i]);
    }
    __syncthreads();

    // context fragment (same for every edge of this batch)
    const float* cd = cdata + b * 64;
    const bf16x8 cfr0 = load8(cd + lg * 8);
    const bf16x8 cfr1 = load8(cd + 32 + lg * 8);

    const size_t bE = (size_t)b * NE;
    const float* ed_b = edata + bE * 64;
    const float* vd_b = vdata + (size_t)b * NV * 64;
    const unsigned short* vt_b = vt + (size_t)b * NV * 64;
    const int* snd_b = snd + bE;
    const int* rcv_b = rcv + bE;
    float* out_b = out + bE * 64;

    for (int t = blk * 8 + w; t < NT; t += 1024) {
        const int e0 = t * 32;
        const int sid0 = snd_b[e0 + l15], sid1 = snd_b[e0 + 16 + l15];
        const int rid0 = rcv_b[e0 + l15], rid1 = rcv_b[e0 + 16 + l15];

        const float* er0 = ed_b + (size_t)(e0 + l15) * 64 + lg * 8;
        const float* er1 = er0 + 16 * 64;

        // ---- gather: edata (nontemporal f32 + convert), vdata (bf16 direct
        //      or f32 fallback). All loads issued upfront (max MLP). ----
        bf16x8 af[6][2];
        af[0][0] = pack8(ntl(er0), ntl(er0 + 4));
        af[0][1] = pack8(ntl(er1), ntl(er1 + 4));
        af[1][0] = pack8(ntl(er0 + 32), ntl(er0 + 36));
        af[1][1] = pack8(ntl(er1 + 32), ntl(er1 + 36));
        if constexpr (BF16V) {
            const unsigned short* s0 = vt_b + (size_t)sid0 * 64 + lg * 8;
            const unsigned short* s1 = vt_b + (size_t)sid1 * 64 + lg * 8;
            const unsigned short* r0 = vt_b + (size_t)rid0 * 64 + lg * 8;
            const unsigned short* r1 = vt_b + (size_t)rid1 * 64 + lg * 8;
            af[2][0] = *(const bf16x8*)(s0);      af[2][1] = *(const bf16x8*)(s1);
            af[3][0] = *(const bf16x8*)(s0 + 32); af[3][1] = *(const bf16x8*)(s1 + 32);
            af[4][0] = *(const bf16x8*)(r0);      af[4][1] = *(const bf16x8*)(r1);
            af[5][0] = *(const bf16x8*)(r0 + 32); af[5][1] = *(const bf16x8*)(r1 + 32);
        } else {
            const float* sr0 = vd_b + (size_t)sid0 * 64 + lg * 8;
            const float* sr1 = vd_b + (size_t)sid1 * 64 + lg * 8;
            const float* rr0 = vd_b + (size_t)rid0 * 64 + lg * 8;
            const float* rr1 = vd_b + (size_t)rid1 * 64 + lg * 8;
            af[2][0] = load8(sr0);      af[2][1] = load8(sr1);
            af[3][0] = load8(sr0 + 32); af[3][1] = load8(sr1 + 32);
            af[4][0] = load8(rr0);      af[4][1] = load8(rr1);
            af[5][0] = load8(rr0 + 32); af[5][1] = load8(rr1 + 32);
        }

        // acc1[ht][et] = h^T tile, init with b1 (row hid = ht*16+lg*4+r)
        f32x4 acc1[8][2];
#pragma unroll
        for (int ht = 0; ht < 8; ++ht) {
            f32x4 bv = ldv(b1 + ht * 16 + lg * 4);
            acc1[ht][0] = bv; acc1[ht][1] = bv;
        }

        // ---- layer 1: h^T[128 x 32] = W1^T @ etin^T ----
#pragma unroll
        for (int kc = 0; kc < 8; ++kc) {
            bf16x8 bc0, bc1;
            if (kc < 6)      { bc0 = af[kc][0]; bc1 = af[kc][1]; }
            else if (kc == 6){ bc0 = cfr0;      bc1 = cfr0; }
            else             { bc0 = cfr1;      bc1 = cfr1; }
#pragma unroll
            for (int ht = 0; ht < 8; ++ht) {
                const int row = ht * 16 + l15;
                const bf16x8 wf = *(const bf16x8*)(lds + W1T_OFF + row * 512 +
                                                   ((kc * 64 + lg * 16) ^ ((row & 7) << 4)));
                acc1[ht][0] = __builtin_amdgcn_mfma_f32_16x16x32_bf16(wf, bc0, acc1[ht][0], 0, 0, 0);
                acc1[ht][1] = __builtin_amdgcn_mfma_f32_16x16x32_bf16(wf, bc1, acc1[ht][1], 0, 0, 0);
            }
        }

        // ---- relu + pack h^T into layer-2 B fragments (no cross-lane ops) ----
        bf16x8 q[2][4];
#pragma unroll
        for (int kc2 = 0; kc2 < 4; ++kc2)
#pragma unroll
            for (int et = 0; et < 2; ++et) {
                f32x4 u = acc1[2 * kc2][et], v = acc1[2 * kc2 + 1][et];
                u32x4 pq;
                pq[0] = pk2(fmaxf(u[0], 0.f), fmaxf(u[1], 0.f));
                pq[1] = pk2(fmaxf(u[2], 0.f), fmaxf(u[3], 0.f));
                pq[2] = pk2(fmaxf(v[0], 0.f), fmaxf(v[1], 0.f));
                pq[3] = pk2(fmaxf(v[2], 0.f), fmaxf(v[3], 0.f));
                q[et][kc2] = __builtin_bit_cast(bf16x8, pq);
            }

        // ---- layer 2: out^T = W2^T @ h^T, acc init with b2 ----
        f32x4 acc2[4][2];
#pragma unroll
        for (int dt = 0; dt < 4; ++dt) {
            f32x4 bv = ldv(b2 + dt * 16 + lg * 4);
            acc2[dt][0] = bv; acc2[dt][1] = bv;
        }
#pragma unroll
        for (int kc2 = 0; kc2 < 4; ++kc2)
#pragma unroll
            for (int dt = 0; dt < 4; ++dt) {
                const int row = dt * 16 + l15;
                const bf16x8 wf = *(const bf16x8*)(lds + W2T_OFF + row * 256 +
                                                   ((kc2 * 64 + lg * 16) ^ ((row & 7) << 4)));
                acc2[dt][0] = __builtin_amdgcn_mfma_f32_16x16x32_bf16(wf, q[0][kc2], acc2[dt][0], 0, 0, 0);
                acc2[dt][1] = __builtin_amdgcn_mfma_f32_16x16x32_bf16(wf, q[1][kc2], acc2[dt][1], 0, 0, 0);
            }

        // ---- store (nontemporal: no write-allocate, less R/W turnaround) ----
        float* ob0 = out_b + (size_t)(e0 + l15) * 64 + lg * 4;
        float* ob1 = ob0 + 16 * 64;
#pragma unroll
        for (int dt = 0; dt < 4; ++dt) {
            nts(ob0 + dt * 16, acc2[dt][0]);
            nts(ob1 + dt * 16, acc2[dt][1]);
        }
    }
}

extern "C" void kernel_launch(void* const* d_in, const int* in_sizes, int n_in,
                              void* d_out, int out_size, void* d_ws, size_t ws_size,
                              hipStream_t stream) {
    const float* vdata = (const float*)d_in[0];
    const float* edata = (const float*)d_in[1];
    const float* cdata = (const float*)d_in[2];
    const float* W1    = (const float*)d_in[3];
    const float* b1    = (const float*)d_in[4];
    const float* W2    = (const float*)d_in[5];
    const float* b2    = (const float*)d_in[6];
    const int*   snd   = (const int*)d_in[7];
    const int*   rcv   = (const int*)d_in[8];
    float* out = (float*)d_out;

    if (ws_size >= VTAB_BYTES) {
        unsigned short* vt = (unsigned short*)d_ws;
        vconv_kernel<<<dim3(2048), dim3(256), 0, stream>>>(vdata, vt);
        edgeblock_kernel<1><<<dim3(512), dim3(512), 0, stream>>>(
            vdata, vt, edata, cdata, W1, b1, W2, b2, snd, rcv, out);
    } else {
        edgeblock_kernel<0><<<dim3(512), dim3(512), 0, stream>>>(
            vdata, (const unsigned short*)d_ws, edata, cdata, W1, b1, W2, b2, snd, rcv, out);
    }
}